// Round 1
// baseline (456.546 us; speedup 1.0000x reference)
//
#include <hip/hip_runtime.h>
#include <math.h>

// HairBundle SDE drift+diffusion, fp32 elementwise.
// Layout: x is [B,5] row-major; out = drift[B,5] flat ++ diffusion[B,5] flat.
// Each thread handles 4 rows = 20 floats = 5 aligned float4 loads + 10 float4 stores.
// B = 8,000,000 is divisible by 4, so no tail path is needed.

__global__ __launch_bounds__(256) void hb_sde_kernel(
    const float* __restrict__ t,
    const float* __restrict__ x,
    float* __restrict__ out,
    int n_groups,        // batch / 4
    long long batch)
{
    const long long tid = (long long)blockIdx.x * blockDim.x + threadIdx.x;
    if (tid >= n_groups) return;

    // wave-uniform sinusoidal drive
    const float force = 0.5f * sinf(6.283185307179586f * t[0] + 0.0f);

    // ---- load 4 rows (20 floats) as 5 float4s ----
    const float4* __restrict__ xv = (const float4*)x + tid * 5;
    float in[20];
    ((float4*)in)[0] = xv[0];
    ((float4*)in)[1] = xv[1];
    ((float4*)in)[2] = xv[2];
    ((float4*)in)[3] = xv[3];
    ((float4*)in)[4] = xv[4];

    float o[20];
#pragma unroll
    for (int r = 0; r < 4; ++r) {
        const float x_hb = in[r*5+0];
        const float x_a  = in[r*5+1];
        const float p_m  = in[r*5+2];
        const float p_gs = in[r*5+3];
        const float p_t  = in[r*5+4];

        // p_o = sigmoid((x_hb - x_a)/DELTA), DELTA = 0.25
        const float p_o  = 1.0f / (1.0f + __expf(-4.0f * (x_hb - x_a)));
        // f_gs = K_GS*(x_hb - x_a - D_GATE*p_o), K_GS=0.75, D_GATE=0.5
        const float f_gs = 0.75f * (x_hb - x_a - 0.5f * p_o);

        o[r*5+0] = -f_gs - 0.6f * x_hb + force;                               // /LAM (=1)
        o[r*5+1] = 0.1f * (f_gs - 0.45f * x_a - 0.35f * (1.0f - 0.9f * p_m)); // /LAM_A (=10)
        o[r*5+2] = 1.2f * p_o * (1.0f - p_m)  - 0.8f * p_m;
        o[r*5+3] = 0.7f * p_o * (1.0f - p_gs) - 0.5f * p_gs;
        o[r*5+4] = 0.3f * p_o * (1.0f - p_t)  - 0.4f * p_t;
    }

    // ---- drift: 5 float4 stores ----
    float4* __restrict__ dv = (float4*)out + tid * 5;
    dv[0] = ((float4*)o)[0];
    dv[1] = ((float4*)o)[1];
    dv[2] = ((float4*)o)[2];
    dv[3] = ((float4*)o)[3];
    dv[4] = ((float4*)o)[4];

    // ---- diffusion: constant pattern [0.05, 0.02, 0, 0, 0] per row.
    // A 20-float (4-row) segment has a fixed float4 decomposition: ----
    float4* __restrict__ gv = (float4*)(out + batch * 5) + tid * 5;
    gv[0] = make_float4(0.05f, 0.02f, 0.0f,  0.0f);
    gv[1] = make_float4(0.0f,  0.05f, 0.02f, 0.0f);
    gv[2] = make_float4(0.0f,  0.0f,  0.05f, 0.02f);
    gv[3] = make_float4(0.0f,  0.0f,  0.0f,  0.05f);
    gv[4] = make_float4(0.02f, 0.0f,  0.0f,  0.0f);
}

extern "C" void kernel_launch(void* const* d_in, const int* in_sizes, int n_in,
                              void* d_out, int out_size, void* d_ws, size_t ws_size,
                              hipStream_t stream) {
    const float* t = (const float*)d_in[0];
    const float* x = (const float*)d_in[1];
    float* out = (float*)d_out;

    const long long batch = (long long)in_sizes[1] / 5;  // 8,000,000
    const int n_groups = (int)(batch / 4);               // 2,000,000 (B % 4 == 0)

    const int block = 256;
    const int grid = (n_groups + block - 1) / block;
    hb_sde_kernel<<<grid, block, 0, stream>>>(t, x, out, n_groups, batch);
}

// Round 3
// 410.854 us; speedup vs baseline: 1.1112x; 1.1112x over previous
//
#include <hip/hip_runtime.h>
#include <math.h>

// HairBundle SDE drift+diffusion, fp32 elementwise, B=8,000,000 rows of 5 vars.
// out = drift[B,5] flat ++ diffusion[B,5] flat.
//
// R2: same as R1 (LDS-transpose staging for per-instruction coalescing) but
// with a clang ext_vector float4 so __builtin_nontemporal_* compiles.

typedef float f4 __attribute__((ext_vector_type(4)));

#define THREADS        128
#define ROWS_PER_BLOCK 512                        // 512 rows * 5 fl = 640 float4
#define F4_PER_BLOCK   (ROWS_PER_BLOCK * 5 / 4)   // 640
#define F4_PER_THREAD  (F4_PER_BLOCK / THREADS)   // 5
#define ROWS_PER_THREAD (ROWS_PER_BLOCK / THREADS) // 4

__global__ __launch_bounds__(THREADS) void hb_sde_kernel(
    const float* __restrict__ t,
    const float* __restrict__ x,
    float* __restrict__ drift,
    float* __restrict__ diff)
{
    __shared__ float lds[ROWS_PER_BLOCK * 5];     // 10 KB

    const int i = threadIdx.x;
    const long long f4base = (long long)blockIdx.x * F4_PER_BLOCK;

    // wave-uniform sinusoidal drive
    const float force = 0.5f * sinf(6.283185307179586f * t[0]);

    // ---- coalesced global -> LDS (lane i handles float4 i, i+128, ...) ----
    const f4* __restrict__ xv = (const f4*)x + f4base;
    f4* lv = (f4*)lds;
#pragma unroll
    for (int k = 0; k < F4_PER_THREAD; ++k)
        lv[i + k * THREADS] = __builtin_nontemporal_load(&xv[i + k * THREADS]);
    __syncthreads();

    // ---- per-thread rows from LDS; overwrite own row with drift ----
#pragma unroll
    for (int r = 0; r < ROWS_PER_THREAD; ++r) {
        const int o = (i * ROWS_PER_THREAD + r) * 5;
        const float x_hb = lds[o + 0];
        const float x_a  = lds[o + 1];
        const float p_m  = lds[o + 2];
        const float p_gs = lds[o + 3];
        const float p_t  = lds[o + 4];

        // p_o = sigmoid((x_hb - x_a)/DELTA), DELTA = 0.25
        const float p_o  = 1.0f / (1.0f + __expf(-4.0f * (x_hb - x_a)));
        // f_gs = K_GS*(x_hb - x_a - D_GATE*p_o)
        const float f_gs = 0.75f * (x_hb - x_a - 0.5f * p_o);

        lds[o + 0] = -f_gs - 0.6f * x_hb + force;
        lds[o + 1] = 0.1f * (f_gs - 0.45f * x_a - 0.35f * (1.0f - 0.9f * p_m));
        lds[o + 2] = 1.2f * p_o * (1.0f - p_m)  - 0.8f * p_m;
        lds[o + 3] = 0.7f * p_o * (1.0f - p_gs) - 0.5f * p_gs;
        lds[o + 4] = 0.3f * p_o * (1.0f - p_t)  - 0.4f * p_t;
    }
    __syncthreads();

    // ---- coalesced LDS -> global drift ----
    f4* __restrict__ dv = (f4*)drift + f4base;
#pragma unroll
    for (int k = 0; k < F4_PER_THREAD; ++k)
        __builtin_nontemporal_store(lv[i + k * THREADS], &dv[i + k * THREADS]);

    // ---- diffusion: constant pattern, direct coalesced stores ----
    // float4 index g covers floats 4g..4g+3; value at float p is c[p%5],
    // c = {0.05, 0.02, 0, 0, 0}. F4_PER_BLOCK=640 is divisible by 5, so
    // g % 5 == (i + k*THREADS) % 5 (block-independent).
    f4* __restrict__ gv = (f4*)diff + f4base;
#pragma unroll
    for (int k = 0; k < F4_PER_THREAD; ++k) {
        const int m = (i + k * THREADS) % 5;
        f4 v;
        v.x = (m == 0) ? 0.05f : ((m == 4) ? 0.02f : 0.0f);
        v.y = (m == 0) ? 0.02f : ((m == 1) ? 0.05f : 0.0f);
        v.z = (m == 1) ? 0.02f : ((m == 2) ? 0.05f : 0.0f);
        v.w = (m == 2) ? 0.02f : ((m == 3) ? 0.05f : 0.0f);
        __builtin_nontemporal_store(v, &gv[i + k * THREADS]);
    }
}

extern "C" void kernel_launch(void* const* d_in, const int* in_sizes, int n_in,
                              void* d_out, int out_size, void* d_ws, size_t ws_size,
                              hipStream_t stream) {
    const float* t = (const float*)d_in[0];
    const float* x = (const float*)d_in[1];
    float* out = (float*)d_out;

    const long long batch = (long long)in_sizes[1] / 5;   // 8,000,000
    float* drift = out;
    float* diff  = out + batch * 5;

    const int nblocks = (int)(batch / ROWS_PER_BLOCK);    // 15625, exact
    hb_sde_kernel<<<nblocks, THREADS, 0, stream>>>(t, x, drift, diff);
}